// Round 6
// baseline (19.199 us; speedup 1.0000x reference)
//
#include <hip/hip_runtime.h>

#define NPART 512
#define BATCH 128
#define MAGIC 0x5F3759DFu

// Quad-split LDS layout: particle p -> region (p&3), slot (p>>2).
// Regions are 192 float4 each (particles mirrored to p<768: slot(p+512)=slot(p)+128).
// Window reads are stride-1 float4 across lanes (conflict-free ds_read_b128),
// with compile-time immediate offsets under full unroll.
//
// grid = 256 blocks = (batch b, half s). block = 1024 threads = (t in [0,128)) x (h in [0,8)).
// Thread (t,h,s): rows i = 4t+r (r=0..3), K in [16X+1, 16X+16], X = 8s+h in [0,16).
// Each unordered pair with circular distance d<256 counted once; d=256 counted
// twice at full weight, corrected by -0.5 in the X==15 threads.
//
// Per-batch fusion: the later of the batch's two blocks (decided by atomicExch
// handshake on done[b]) combines both partials and writes out[b]. done[b] is
// self-resetting; MAGIC != 0xAAAAAAAA poison, so the first timed replay and all
// later replays pick exactly one finisher.

__global__ __launch_bounds__(1024, 4) void lj_fused(
    const float* __restrict__ x, float* __restrict__ out,
    float* __restrict__ wsp, unsigned int* __restrict__ done) {
    const int bid = blockIdx.x;
    const int b = bid >> 1;
    const int s = bid & 1;
    const int tid = threadIdx.x;
    const int t = tid & 127;
    const int h = tid >> 7;

    __shared__ float4 sp[768];       // 4 regions x 192 float4 = 12 KB
    __shared__ float wred[16];
    __shared__ float wspr[2][4];

    // ---- stage 1536 floats (+768 mirror floats) into quad-split layout ----
    const float* xb = x + (size_t)b * (NPART * 3);
    float* spf = reinterpret_cast<float*>(sp);
    {
        const int idx = tid;                 // 0..1023
        const float v = xb[idx];
        const int p = idx / 3;
        const int c = idx - 3 * p;
        const int sl = (p & 3) * 192 + (p >> 2);
        spf[4 * sl + c] = v;
        if (p < 256) spf[4 * (sl + 128) + c] = v;   // mirror p+512
    }
    if (tid < 512) {
        const int idx = tid + 1024;          // 1024..1535 (p >= 341, no mirror)
        const float v = xb[idx];
        const int p = idx / 3;
        const int c = idx - 3 * p;
        const int sl = (p & 3) * 192 + (p >> 2);
        spf[4 * sl + c] = v;
    }
    __syncthreads();

    // region pointers at slot t
    const float4* R0 = sp + t;
    const float4* R1 = sp + 192 + t;
    const float4* R2 = sp + 384 + t;
    const float4* R3 = sp + 576 + t;

    const float4 pi0 = R0[0];   // particle 4t
    const float4 pi1 = R1[0];   // particle 4t+1
    const float4 pi2 = R2[0];   // particle 4t+2
    const float4 pi3 = R3[0];   // particle 4t+3

    const int X = 8 * s + h;     // 0..15 ; k0 = 16X+1 ; J = 4t + k0
    const int B4 = 4 * X;        // window slot offset (J>>2 = t + 4X)

    float accA = 0.0f, accB = 0.0f;

    // acc += i6*(i6-1) ; pot = 4*acc
    #define PT(PI, W, ACC) do {                                   \
        const float dx_ = (PI).x - (W).x;                         \
        const float dy_ = (PI).y - (W).y;                         \
        const float dz_ = (PI).z - (W).z;                         \
        const float r2_ = fmaf(dx_, dx_, fmaf(dy_, dy_, dz_ * dz_)); \
        const float i2_ = __builtin_amdgcn_rcpf(r2_);             \
        const float i6_ = i2_ * i2_ * i2_;                        \
        ACC = fmaf(i6_, i6_ - 1.0f, ACC);                         \
    } while (0)

    // sliding window w[m] holds particle j = J + m  (J = 4t + 16X + 1)
    float4 w[19];
    w[0] = R1[B4];               // j = J   : region 1, slot t+4X
    w[1] = R2[B4];               // j = J+1 : region 2
    w[2] = R3[B4];               // j = J+2 : region 3
    #pragma unroll
    for (int m = 0; m < 16; ++m) {
        const int q = B4 + 1 + (m >> 2);   // slot offset of j = J+3+m
        const int rg = m & 3;              // region of j = J+3+m
        w[m + 3] = (rg == 0) ? R0[q] : (rg == 1) ? R1[q] : (rg == 2) ? R2[q] : R3[q];
        PT(pi0, w[m], accA);      // K = k0 + m
        PT(pi1, w[m + 1], accA);
        PT(pi2, w[m + 2], accB);
        PT(pi3, w[m + 3], accB);
    }

    // K=256 pairs (X==15, m==15) were counted at full weight from both
    // endpoints globally -> subtract half once per row. j = 4t+r+256.
    if (X == 15) {
        #define CORR(PI, W, ACC) do {                             \
            const float dx_ = (PI).x - (W).x;                     \
            const float dy_ = (PI).y - (W).y;                     \
            const float dz_ = (PI).z - (W).z;                     \
            const float r2_ = fmaf(dx_, dx_, fmaf(dy_, dy_, dz_ * dz_)); \
            const float i2_ = __builtin_amdgcn_rcpf(r2_);         \
            const float i6_ = i2_ * i2_ * i2_;                    \
            ACC -= 0.5f * i6_ * (i6_ - 1.0f);                     \
        } while (0)
        CORR(pi0, R0[64], accA);
        CORR(pi1, R1[64], accA);
        CORR(pi2, R2[64], accB);
        CORR(pi3, R3[64], accB);
        #undef CORR
    }
    #undef PT

    float pot = 4.0f * (accA + accB);

    #pragma unroll
    for (int off = 32; off; off >>= 1) pot += __shfl_down(pot, off, 64);

    // Harmonic COM restraint: X==0 threads (s==0, h==0) own particles
    // 4t..4t+3 exactly once -> waves 0,1 of the s==0 block.
    float sx = 0.0f, sy = 0.0f, sz = 0.0f, ssq = 0.0f;
    if (X == 0) {
        sx = pi0.x + pi1.x + pi2.x + pi3.x;
        sy = pi0.y + pi1.y + pi2.y + pi3.y;
        sz = pi0.z + pi1.z + pi2.z + pi3.z;
        ssq = pi0.x * pi0.x + pi0.y * pi0.y + pi0.z * pi0.z
            + pi1.x * pi1.x + pi1.y * pi1.y + pi1.z * pi1.z
            + pi2.x * pi2.x + pi2.y * pi2.y + pi2.z * pi2.z
            + pi3.x * pi3.x + pi3.y * pi3.y + pi3.z * pi3.z;
        #pragma unroll
        for (int off = 32; off; off >>= 1) {
            sx  += __shfl_down(sx,  off, 64);
            sy  += __shfl_down(sy,  off, 64);
            sz  += __shfl_down(sz,  off, 64);
            ssq += __shfl_down(ssq, off, 64);
        }
    }

    const int wave = tid >> 6;
    const int lane = tid & 63;
    if (lane == 0) {
        wred[wave] = pot;
        if (wave < 2 && s == 0) {
            wspr[wave][0] = sx; wspr[wave][1] = sy;
            wspr[wave][2] = sz; wspr[wave][3] = ssq;
        }
    }
    __syncthreads();

    if (tid == 0) {
        float P = 0.0f;
        #pragma unroll
        for (int w2 = 0; w2 < 16; ++w2) P += wred[w2];
        float res = P;
        if (s == 0) {
            const float SX = wspr[0][0] + wspr[1][0];
            const float SY = wspr[0][1] + wspr[1][1];
            const float SZ = wspr[0][2] + wspr[1][2];
            const float SS = wspr[0][3] + wspr[1][3];
            // 0.5*K_spring*sum(rel^2), K_spring=0.5 -> 0.25*(ssq - |S|^2/N)
            res += 0.25f * (SS - (SX * SX + SY * SY + SZ * SZ) * (1.0f / NPART));
        }

        // ---- per-batch handshake: later block combines and writes out[b] ----
        __hip_atomic_store(&wsp[bid], res, __ATOMIC_RELEASE,
                           __HIP_MEMORY_SCOPE_AGENT);
        const unsigned int old = __hip_atomic_exchange(
            &done[b], MAGIC, __ATOMIC_ACQ_REL, __HIP_MEMORY_SCOPE_AGENT);
        if (old == MAGIC) {
            const float other = __hip_atomic_load(
                &wsp[bid ^ 1], __ATOMIC_ACQUIRE, __HIP_MEMORY_SCOPE_AGENT);
            out[b] = -(res + other);
            __hip_atomic_store(&done[b], 0u, __ATOMIC_RELAXED,
                               __HIP_MEMORY_SCOPE_AGENT);
        }
    }
}

extern "C" void kernel_launch(void* const* d_in, const int* in_sizes, int n_in,
                              void* d_out, int out_size, void* d_ws, size_t ws_size,
                              hipStream_t stream) {
    const float* x = (const float*)d_in[0];
    float* out = (float*)d_out;
    float* wsp = (float*)d_ws;                                  // 256 partials
    unsigned int* done = (unsigned int*)((char*)d_ws + 4096);   // 128 flags

    lj_fused<<<BATCH * 2, 1024, 0, stream>>>(x, out, wsp, done);
}

// Round 7
// 13.541 us; speedup vs baseline: 1.4178x; 1.4178x over previous
//
#include <hip/hip_runtime.h>

typedef float v2f __attribute__((ext_vector_type(2)));

#define NPART 512
#define BATCH 128

// SoA quad-split LDS: coord c of particle p lives at S[c][p&3][p>>2].
// Mirror p+512 == p for p<256 at slot (p>>2)+128. A packed window read
// (particles j, j+4) = adjacent slots of one region -> ds_read2_b32,
// stride-1 across lanes (conflict-free).
//
// grid = 256 = (batch b, half s); block = 1024 = (t in [0,128)) x (h in [0,8)).
// Thread (t,h,s): rows i = 4t+r (r=0..3), K in [16X+1, 16X+16], X = 8s+h.
// Packed over (K, K+4): delta in {0..3, 8..11}. Window value u = r+delta+1
// gives region g=u&3, slot tq+(u>>2) with tq = t+4X; each read serves up to
// 4 rows. K=256 double-count corrected at X==15 with weight -1/2.

__global__ __launch_bounds__(1024, 4) void lj_main(
    const float* __restrict__ x, float* __restrict__ ws) {
    const int bid = blockIdx.x;
    const int b = bid >> 1;
    const int s = bid & 1;
    const int tid = threadIdx.x;
    const int t = tid & 127;
    const int h = tid >> 7;

    __shared__ float S[3][4][192];   // 9216 B
    __shared__ float wred[16];
    __shared__ float wspr[2][4];

    // ---- stage 1536 floats (+ mirror) into SoA quad-split layout ----
    const float* xb = x + (size_t)b * (NPART * 3);
    {
        const int idx = tid;                 // 0..1023
        const float v = xb[idx];
        const int p = idx / 3;
        const int c = idx - 3 * p;
        S[c][p & 3][p >> 2] = v;
        if (p < 256) S[c][p & 3][(p >> 2) + 128] = v;
    }
    if (tid < 512) {
        const int idx = tid + 1024;          // p >= 341, no mirror
        const float v = xb[idx];
        const int p = idx / 3;
        const int c = idx - 3 * p;
        S[c][p & 3][p >> 2] = v;
    }
    __syncthreads();

    const int X = 8 * s + h;     // 0..15
    const int tq = t + 4 * X;

    // own particles 4t+r
    const float pix0 = S[0][0][t], piy0 = S[1][0][t], piz0 = S[2][0][t];
    const float pix1 = S[0][1][t], piy1 = S[1][1][t], piz1 = S[2][1][t];
    const float pix2 = S[0][2][t], piy2 = S[1][2][t], piz2 = S[2][2][t];
    const float pix3 = S[0][3][t], piy3 = S[1][3][t], piz3 = S[2][3][t];

    const v2f px0 = {pix0, pix0}, py0 = {piy0, piy0}, pz0 = {piz0, piz0};
    const v2f px1 = {pix1, pix1}, py1 = {piy1, piy1}, pz1 = {piz1, piz1};
    const v2f px2 = {pix2, pix2}, py2 = {piy2, piy2}, pz2 = {piz2, piz2};
    const v2f px3 = {pix3, pix3}, py3 = {piy3, piy3}, pz3 = {piz3, piz3};

    v2f acc0 = {0.f, 0.f}, acc1 = {0.f, 0.f}, acc2 = {0.f, 0.f}, acc3 = {0.f, 0.f};
    const v2f vone = {1.0f, 1.0f};

    // packed pair term: rows' two pairs (K, K+4); paired rcp (1 trans / 2 pairs)
    #define PPK(r, XW, YW, ZW) do {                                        \
        const v2f dX_ = px##r - (XW);                                      \
        const v2f dY_ = py##r - (YW);                                      \
        const v2f dZ_ = pz##r - (ZW);                                      \
        const v2f R2_ = __builtin_elementwise_fma(dX_, dX_,                \
                          __builtin_elementwise_fma(dY_, dY_, dZ_ * dZ_)); \
        const float pr_ = R2_.x * R2_.y;                                   \
        const float rt_ = __builtin_amdgcn_rcpf(pr_);                      \
        v2f I2_; I2_.x = R2_.y * rt_; I2_.y = R2_.x * rt_;                 \
        const v2f I6_ = I2_ * I2_ * I2_;                                   \
        acc##r = __builtin_elementwise_fma(I6_, I6_ - vone, acc##r);       \
    } while (0)

    #define LOADU(G, QC)                                                   \
        v2f Xw; Xw.x = S[0][G][tq + (QC)]; Xw.y = S[0][G][tq + (QC) + 1];  \
        v2f Yw; Yw.x = S[1][G][tq + (QC)]; Yw.y = S[1][G][tq + (QC) + 1];  \
        v2f Zw; Zw.x = S[2][G][tq + (QC)]; Zw.y = S[2][G][tq + (QC) + 1];

    { LOADU(1, 0) PPK(0, Xw, Yw, Zw); }                                             // u=1
    { LOADU(2, 0) PPK(0, Xw, Yw, Zw); PPK(1, Xw, Yw, Zw); }                         // u=2
    { LOADU(3, 0) PPK(0, Xw, Yw, Zw); PPK(1, Xw, Yw, Zw); PPK(2, Xw, Yw, Zw); }     // u=3
    { LOADU(0, 1) PPK(0, Xw, Yw, Zw); PPK(1, Xw, Yw, Zw); PPK(2, Xw, Yw, Zw); PPK(3, Xw, Yw, Zw); } // u=4
    { LOADU(1, 1) PPK(1, Xw, Yw, Zw); PPK(2, Xw, Yw, Zw); PPK(3, Xw, Yw, Zw); }     // u=5
    { LOADU(2, 1) PPK(2, Xw, Yw, Zw); PPK(3, Xw, Yw, Zw); }                         // u=6
    { LOADU(3, 1) PPK(3, Xw, Yw, Zw); }                                             // u=7
    { LOADU(1, 2) PPK(0, Xw, Yw, Zw); }                                             // u=9
    { LOADU(2, 2) PPK(0, Xw, Yw, Zw); PPK(1, Xw, Yw, Zw); }                         // u=10
    { LOADU(3, 2) PPK(0, Xw, Yw, Zw); PPK(1, Xw, Yw, Zw); PPK(2, Xw, Yw, Zw); }     // u=11
    { LOADU(0, 3) PPK(0, Xw, Yw, Zw); PPK(1, Xw, Yw, Zw); PPK(2, Xw, Yw, Zw); PPK(3, Xw, Yw, Zw); } // u=12
    { LOADU(1, 3) PPK(1, Xw, Yw, Zw); PPK(2, Xw, Yw, Zw); PPK(3, Xw, Yw, Zw); }     // u=13
    { LOADU(2, 3) PPK(2, Xw, Yw, Zw); PPK(3, Xw, Yw, Zw); }                         // u=14
    { LOADU(3, 3) PPK(3, Xw, Yw, Zw); }                                             // u=15
    #undef LOADU
    #undef PPK

    float corr = 0.0f;
    // K=256 (X==15, second half of delta=11 pair) counted from both endpoints
    // globally -> subtract half once per row. j = 4t+r+256 -> region r, slot t+64.
    if (X == 15) {
        #define CORR(r) do {                                               \
            const float wx = S[0][r][t + 64];                              \
            const float wy = S[1][r][t + 64];                              \
            const float wz = S[2][r][t + 64];                              \
            const float dx_ = pix##r - wx;                                 \
            const float dy_ = piy##r - wy;                                 \
            const float dz_ = piz##r - wz;                                 \
            const float r2_ = fmaf(dx_, dx_, fmaf(dy_, dy_, dz_ * dz_));   \
            const float i2_ = __builtin_amdgcn_rcpf(r2_);                  \
            const float i6_ = i2_ * i2_ * i2_;                             \
            corr -= 0.5f * i6_ * (i6_ - 1.0f);                             \
        } while (0)
        CORR(0); CORR(1); CORR(2); CORR(3);
        #undef CORR
    }

    float pot = 4.0f * (acc0.x + acc0.y + acc1.x + acc1.y +
                        acc2.x + acc2.y + acc3.x + acc3.y + corr);

    #pragma unroll
    for (int off = 32; off; off >>= 1) pot += __shfl_down(pot, off, 64);

    // Harmonic COM restraint: X==0 threads own particles 4t..4t+3 exactly once.
    float sx = 0.0f, sy = 0.0f, sz = 0.0f, ssq = 0.0f;
    if (X == 0) {
        sx = pix0 + pix1 + pix2 + pix3;
        sy = piy0 + piy1 + piy2 + piy3;
        sz = piz0 + piz1 + piz2 + piz3;
        ssq = pix0 * pix0 + piy0 * piy0 + piz0 * piz0
            + pix1 * pix1 + piy1 * piy1 + piz1 * piz1
            + pix2 * pix2 + piy2 * piy2 + piz2 * piz2
            + pix3 * pix3 + piy3 * piy3 + piz3 * piz3;
        #pragma unroll
        for (int off = 32; off; off >>= 1) {
            sx  += __shfl_down(sx,  off, 64);
            sy  += __shfl_down(sy,  off, 64);
            sz  += __shfl_down(sz,  off, 64);
            ssq += __shfl_down(ssq, off, 64);
        }
    }

    const int wave = tid >> 6;
    const int lane = tid & 63;
    if (lane == 0) {
        wred[wave] = pot;
        if (wave < 2 && s == 0) {
            wspr[wave][0] = sx; wspr[wave][1] = sy;
            wspr[wave][2] = sz; wspr[wave][3] = ssq;
        }
    }
    __syncthreads();

    if (tid == 0) {
        float P = 0.0f;
        #pragma unroll
        for (int w2 = 0; w2 < 16; ++w2) P += wred[w2];
        float res = P;
        if (s == 0) {
            const float SX = wspr[0][0] + wspr[1][0];
            const float SY = wspr[0][1] + wspr[1][1];
            const float SZ = wspr[0][2] + wspr[1][2];
            const float SS = wspr[0][3] + wspr[1][3];
            // 0.5*K_spring*sum(rel^2), K_spring=0.5 -> 0.25*(ssq - |S|^2/N)
            res += 0.25f * (SS - (SX * SX + SY * SY + SZ * SZ) * (1.0f / NPART));
        }
        ws[bid] = res;
    }
}

__global__ void lj_combine(const float* __restrict__ ws,
                           float* __restrict__ out) {
    const int t = threadIdx.x;
    if (t < BATCH) out[t] = -(ws[2 * t] + ws[2 * t + 1]);
}

extern "C" void kernel_launch(void* const* d_in, const int* in_sizes, int n_in,
                              void* d_out, int out_size, void* d_ws, size_t ws_size,
                              hipStream_t stream) {
    const float* x = (const float*)d_in[0];
    float* out = (float*)d_out;
    float* pw = (float*)d_ws;   // 256 partials

    lj_main<<<BATCH * 2, 1024, 0, stream>>>(x, pw);
    lj_combine<<<1, 128, 0, stream>>>(pw, out);
}